// Round 12
// baseline (122.522 us; speedup 1.0000x reference)
//
#include <hip/hip_runtime.h>
#include <math.h>

#define B 2
#define N 512
#define DIM 256
#define HEADS 8
#define DHEAD 32
#define INNER 256
#define DEPTH 2
#define SCALE 0.17677669529663687f
#define L2INVF 0.8304820237218406f   // log2(10000)/16

// ---- block-wide sum over 256 threads (4 waves), result broadcast to all ----
__device__ __forceinline__ float block_sum256(float v, float* red4) {
    #pragma unroll
    for (int o = 32; o; o >>= 1) v += __shfl_xor(v, o);
    int tid = threadIdx.x;
    __syncthreads();
    if ((tid & 63) == 0) red4[tid >> 6] = v;
    __syncthreads();
    return red4[0] + red4[1] + red4[2] + red4[3];
}

// ---- wave-wide (64-lane) sum, broadcast ----
__device__ __forceinline__ float wave_sum(float v) {
    #pragma unroll
    for (int o = 32; o; o >>= 1) v += __shfl_xor(v, o);
    return v;
}

// ========== QKV GEMM with fused input prologue + rotary epilogue ==========
// layer 0 prologue: encode(x,t)+LN0 -> Ah (writes nodes at nt==0)
// layer 1 prologue: gate(obuf,nodes)+residual+LN1 -> Ah (writes nodes2 at nt==0)
#define AHS 260   // Ah row stride (floats): 16B-aligned, breaks bank periodicity
__global__ __launch_bounds__(256, 3)
void k_qkv(const float* __restrict__ x, const float* __restrict__ t,
           const float* __restrict__ Wenc,
           const float* __restrict__ obuf, const float* __restrict__ nodes,
           float* __restrict__ nodes2, const float* __restrict__ Wg,
           const float* __restrict__ ln_g, const float* __restrict__ ln_b,
           const float* __restrict__ Wq, const float* __restrict__ bq,
           const float* __restrict__ Wkv, const float* __restrict__ bkv,
           const float* __restrict__ We, const float* __restrict__ be,
           float* __restrict__ qbuf, float* __restrict__ kbuf, float* __restrict__ vbuf,
           float* __restrict__ qwe, float* __restrict__ qbe, int layer) {
    __shared__ float Ah[32 * AHS];     // 32 input rows (post-LN), ~33 KB
    __shared__ float Bs[64 * 64];      // weight tile, 16 KB (reused as rotary scratch)

    int tid = threadIdx.x;
    int mt = blockIdx.x & 31;
    int nt = blockIdx.x >> 5;          // 0..11
    int n0 = nt * 64;

    // ---------- prologue: build this block's 32 input rows ----------
    {
        int wv = tid >> 6, lane = tid & 63;
        int c0 = lane * 4;
        for (int rr = wv; rr < 32; rr += 4) {
            int row = mt*32 + rr;
            float4 v;
            if (layer == 0) {
                float x0 = x[row*3+0], x1 = x[row*3+1], x2 = x[row*3+2], tt = t[row];
                float4 w0 = *(const float4*)&Wenc[c0];
                float4 w1 = *(const float4*)&Wenc[DIM + c0];
                float4 w2 = *(const float4*)&Wenc[2*DIM + c0];
                float4 w3 = *(const float4*)&Wenc[3*DIM + c0];
                v.x = x0*w0.x + x1*w1.x + x2*w2.x + tt*w3.x;
                v.y = x0*w0.y + x1*w1.y + x2*w2.y + tt*w3.y;
                v.z = x0*w0.z + x1*w1.z + x2*w2.z + tt*w3.z;
                v.w = x0*w0.w + x1*w1.w + x2*w2.w + tt*w3.w;
                if (nt == 0) *(float4*)&nodes2[(size_t)row*DIM + c0] = v;  // nodes2 holds encode for l0
            } else {
                float4 o4 = *(const float4*)&obuf[(size_t)row*DIM + c0];
                float4 nd = *(const float4*)&nodes[(size_t)row*DIM + c0];
                const float* Wgl = Wg;  // layer-0 gate weights
                float4 g1 = *(const float4*)&Wgl[c0];
                float4 g2 = *(const float4*)&Wgl[DIM + c0];
                float4 g3 = *(const float4*)&Wgl[2*DIM + c0];
                float sp = o4.x*g1.x + nd.x*g2.x + (o4.x-nd.x)*g3.x
                         + o4.y*g1.y + nd.y*g2.y + (o4.y-nd.y)*g3.y
                         + o4.z*g1.z + nd.z*g2.z + (o4.z-nd.z)*g3.z
                         + o4.w*g1.w + nd.w*g2.w + (o4.w-nd.w)*g3.w;
                sp = wave_sum(sp);
                float gate = 1.0f/(1.0f + __expf(-sp));
                v.x = o4.x*gate + nd.x*(1.f-gate);
                v.y = o4.y*gate + nd.y*(1.f-gate);
                v.z = o4.z*gate + nd.z*(1.f-gate);
                v.w = o4.w*gate + nd.w*(1.f-gate);
                if (nt == 0) *(float4*)&nodes2[(size_t)row*DIM + c0] = v;  // post-l0 residual
            }
            // LN(layer)
            float mean = wave_sum(v.x + v.y + v.z + v.w) * (1.0f/DIM);
            float4 cc = make_float4(v.x-mean, v.y-mean, v.z-mean, v.w-mean);
            float vs = wave_sum(cc.x*cc.x + cc.y*cc.y + cc.z*cc.z + cc.w*cc.w);
            float rs = 1.0f/sqrtf(vs*(1.0f/DIM) + 1e-5f);
            float4 lg = *(const float4*)&ln_g[layer*DIM + c0];
            float4 lb = *(const float4*)&ln_b[layer*DIM + c0];
            Ah[rr*AHS + c0+0] = cc.x*rs*lg.x + lb.x;
            Ah[rr*AHS + c0+1] = cc.y*rs*lg.y + lb.y;
            Ah[rr*AHS + c0+2] = cc.z*rs*lg.z + lb.z;
            Ah[rr*AHS + c0+3] = cc.w*rs*lg.w + lb.w;
        }
    }
    __syncthreads();

    // ---------- tiled GEMM: C[32 x 64] = Ah[32 x 256] @ W[256 x 64] ----------
    int tx = tid & 15, ty = tid >> 4;
    const float* Wsrc; int wstride;
    if (n0 < 256) { Wsrc = Wq  + (size_t)layer*256*256 + n0;        wstride = 256; }
    else          { Wsrc = Wkv + (size_t)layer*256*512 + (n0-256);  wstride = 512; }

    float acc[2][4] = {{0,0,0,0},{0,0,0,0}};
    int bn4 = tid & 15, bk = tid >> 4;

    for (int kt = 0; kt < 4; ++kt) {
        int kbase = kt * 64;
        if (kt) __syncthreads();
        #pragma unroll
        for (int p = 0; p < 4; ++p) {
            int k = bk + p*16;
            float4 v = *(const float4*)(Wsrc + (size_t)(kbase + k)*wstride + bn4*4);
            *(float4*)&Bs[k*64 + bn4*4] = v;
        }
        __syncthreads();
        #pragma unroll 8
        for (int k = 0; k < 64; ++k) {
            float ax = Ah[(ty*2+0)*AHS + kbase + k];
            float ay = Ah[(ty*2+1)*AHS + kbase + k];
            float4 b = *(const float4*)&Bs[k*64 + tx*4];
            acc[0][0] += ax*b.x; acc[0][1] += ax*b.y; acc[0][2] += ax*b.z; acc[0][3] += ax*b.w;
            acc[1][0] += ay*b.x; acc[1][1] += ay*b.y; acc[1][2] += ay*b.z; acc[1][3] += ay*b.w;
        }
    }

    int row = mt*32 + ty*2;
    int n = n0 + tx*4;

    float4 bias4;
    if (n0 < 256) bias4 = *(const float4*)&bq[layer*256 + n];
    else          bias4 = *(const float4*)&bkv[layer*512 + (n - 256)];
    #pragma unroll
    for (int r = 0; r < 2; ++r) {
        acc[r][0] += bias4.x; acc[r][1] += bias4.y; acc[r][2] += bias4.z; acc[r][3] += bias4.w;
    }

    if (n0 >= 512) {                   // V tile: plain store
        #pragma unroll
        for (int r = 0; r < 2; ++r) {
            float4 o = make_float4(acc[r][0], acc[r][1], acc[r][2], acc[r][3]);
            *(float4*)&vbuf[(size_t)(row + r)*256 + (n - 512)] = o;
        }
        return;
    }

    // ---------- rotary epilogue (q and k tiles) ----------
    float* sh = Bs;                    // [32][68] scratch
    __syncthreads();
    #pragma unroll
    for (int r = 0; r < 2; ++r)
        #pragma unroll
        for (int c = 0; c < 4; ++c)
            sh[(ty*2 + r)*68 + tx*4 + c] = acc[r][c];
    __syncthreads();

    // inline angle tables: jj depends on c only, ii on r only
    float ca_[2][4], sa_[2][4];
    #pragma unroll
    for (int r = 0; r < 2; ++r) {
        int ii = (row + r) & (N-1);
        #pragma unroll
        for (int c = 0; c < 4; ++c) {
            int jj = (tx*4 + c) & 15;
            float invf = exp2f(-(float)jj * L2INVF);
            float ang = (float)ii * invf;
            sincosf(ang, &sa_[r][c], &ca_[r][c]);
        }
    }

    float wep[2] = {0.f, 0.f}, bep[2] = {0.f, 0.f};
    float val[2][4];
    #pragma unroll
    for (int r = 0; r < 2; ++r) {
        #pragma unroll
        for (int c = 0; c < 4; ++c) {
            int tc = tx*4 + c;
            int dd = tc & 31;
            int ptc = (dd < 16) ? tc + 16 : tc - 16;
            float sgn = (dd < 16) ? -1.f : 1.f;
            float partner = sh[(ty*2 + r)*68 + ptc];
            float rot = acc[r][c]*ca_[r][c] + sgn*partner*sa_[r][c];
            val[r][c] = rot;
            if (n0 < 256) {
                wep[r] += rot * We[layer*256 + n0 + tc];
                bep[r] += rot * be[layer*256 + n0 + tc];
            }
        }
    }

    float* dst = (n0 < 256) ? qbuf : kbuf;
    int coln = (n0 < 256) ? n : n - 256;
    #pragma unroll
    for (int r = 0; r < 2; ++r) {
        float4 o = make_float4(val[r][0], val[r][1], val[r][2], val[r][3]);
        *(float4*)&dst[(size_t)(row + r)*256 + coln] = o;
    }

    if (n0 < 256) {                    // qwe/qbe: reduce over tx octet
        #pragma unroll
        for (int r = 0; r < 2; ++r) {
            wep[r] += __shfl_xor(wep[r], 1); bep[r] += __shfl_xor(bep[r], 1);
            wep[r] += __shfl_xor(wep[r], 2); bep[r] += __shfl_xor(bep[r], 2);
            wep[r] += __shfl_xor(wep[r], 4); bep[r] += __shfl_xor(bep[r], 4);
        }
        if ((tid & 7) == 0) {
            int h = nt*2 + (tx >> 3);
            int bb = row >> 9;
            #pragma unroll
            for (int r = 0; r < 2; ++r) {
                int ii = (row + r) & (N-1);
                qwe[(bb*HEADS + h)*N + ii] = wep[r];
                qbe[(bb*HEADS + h)*N + ii] = bep[r];
            }
        }
    }
}

// ========== attention: TI=16, 2 i-rows/thread, dist computed inline ==========
#define TI 16
__global__ __launch_bounds__(256, 2)
void k_attn(const float* __restrict__ x,
            const float* __restrict__ qbuf, const float* __restrict__ kbuf,
            const float* __restrict__ vbuf,
            const float* __restrict__ qwe, const float* __restrict__ qbe,
            const float* __restrict__ We, const float* __restrict__ be,
            float* __restrict__ attnout, int layer) {
    __shared__ float Tt[32 * 128];
    __shared__ float xs[N * 3];           // this batch's coords, 6 KB

    int t = threadIdx.x;
    int g = t & 31;
    int r = t >> 5;
    int bid = blockIdx.x;
    int itile = bid & 31;
    int h = (bid >> 5) & (HEADS-1);
    int b = bid >> 8;
    int i0 = itile * TI + r;
    int i1 = i0 + 8;

    int scol = t & 127;
    int d0   = (t >> 7) * 16;

    // stage coords
    for (int f = t; f < N*3; f += 256) xs[f] = x[b*N*3 + f];
    __syncthreads();
    float xa0 = xs[i0*3+0], xa1 = xs[i0*3+1], xa2 = xs[i0*3+2];
    float xb0 = xs[i1*3+0], xb1 = xs[i1*3+1], xb2 = xs[i1*3+2];

    float q0[32], q1[32];
    {
        const float4* qp0 = (const float4*)(qbuf + (size_t)(b*N + i0) * INNER + h * DHEAD);
        const float4* qp1 = (const float4*)(qbuf + (size_t)(b*N + i1) * INNER + h * DHEAD);
        #pragma unroll
        for (int c = 0; c < 8; ++c) {
            float4 v0 = qp0[c], v1 = qp1[c];
            q0[c*4+0] = v0.x; q0[c*4+1] = v0.y; q0[c*4+2] = v0.z; q0[c*4+3] = v0.w;
            q1[c*4+0] = v1.x; q1[c*4+1] = v1.y; q1[c*4+2] = v1.z; q1[c*4+3] = v1.w;
        }
    }
    float qw0 = qwe[(b*HEADS + h)*N + i0], qb0 = qbe[(b*HEADS + h)*N + i0];
    float qw1 = qwe[(b*HEADS + h)*N + i1], qb1 = qbe[(b*HEADS + h)*N + i1];

    const float* kbase = kbuf + (size_t)b*N*INNER + h*DHEAD;
    const float* vbase = vbuf + (size_t)b*N*INNER + h*DHEAD;

    float sim0[16], sim1[16];

    #pragma unroll
    for (int jt = 0; jt < 4; ++jt) {
        if (jt) __syncthreads();
        {
            const float* src = kbase + (size_t)(jt*128 + scol) * INNER + d0;
            float4 a0 = *(const float4*)(src + 0);
            float4 a1 = *(const float4*)(src + 4);
            float4 a2 = *(const float4*)(src + 8);
            float4 a3 = *(const float4*)(src + 12);
            Tt[(d0+ 0)*128 + scol] = a0.x; Tt[(d0+ 1)*128 + scol] = a0.y;
            Tt[(d0+ 2)*128 + scol] = a0.z; Tt[(d0+ 3)*128 + scol] = a0.w;
            Tt[(d0+ 4)*128 + scol] = a1.x; Tt[(d0+ 5)*128 + scol] = a1.y;
            Tt[(d0+ 6)*128 + scol] = a1.z; Tt[(d0+ 7)*128 + scol] = a1.w;
            Tt[(d0+ 8)*128 + scol] = a2.x; Tt[(d0+ 9)*128 + scol] = a2.y;
            Tt[(d0+10)*128 + scol] = a2.z; Tt[(d0+11)*128 + scol] = a2.w;
            Tt[(d0+12)*128 + scol] = a3.x; Tt[(d0+13)*128 + scol] = a3.y;
            Tt[(d0+14)*128 + scol] = a3.z; Tt[(d0+15)*128 + scol] = a3.w;
        }
        __syncthreads();
        float4 s0 = make_float4(0.f,0.f,0.f,0.f);
        float4 s1 = make_float4(0.f,0.f,0.f,0.f);
        #pragma unroll
        for (int d = 0; d < 32; ++d) {
            float4 kv = *(const float4*)&Tt[d*128 + g*4];
            float qa = q0[d], qc = q1[d];
            s0.x += qa*kv.x; s0.y += qa*kv.y; s0.z += qa*kv.z; s0.w += qa*kv.w;
            s1.x += qc*kv.x; s1.y += qc*kv.y; s1.z += qc*kv.z; s1.w += qc*kv.w;
        }
        #pragma unroll
        for (int u = 0; u < 4; ++u) {
            int j = jt*128 + g*4 + u;
            float e0 = xa0 - xs[j*3+0], e1 = xa1 - xs[j*3+1], e2 = xa2 - xs[j*3+2];
            float ss = e0*e0 + e1*e1 + e2*e2;
            float dv0 = (ss > 0.f) ? sqrtf(ss) : 0.f;
            float f0 = xb0 - xs[j*3+0], f1 = xb1 - xs[j*3+1], f2 = xb2 - xs[j*3+2];
            float tt2 = f0*f0 + f1*f1 + f2*f2;
            float dv1 = (tt2 > 0.f) ? sqrtf(tt2) : 0.f;
            float sv0 = (u==0) ? s0.x : (u==1) ? s0.y : (u==2) ? s0.z : s0.w;
            float sv1 = (u==0) ? s1.x : (u==1) ? s1.y : (u==2) ? s1.z : s1.w;
            sim0[jt*4+u] = (sv0 + dv0*qw0 + qb0) * SCALE;
            sim1[jt*4+u] = (sv1 + dv1*qw1 + qb1) * SCALE;
        }
    }

    float mx0 = -1e30f, mx1 = -1e30f;
    #pragma unroll
    for (int v = 0; v < 16; ++v) { mx0 = fmaxf(mx0, sim0[v]); mx1 = fmaxf(mx1, sim1[v]); }
    #pragma unroll
    for (int o = 1; o <= 16; o <<= 1) {
        mx0 = fmaxf(mx0, __shfl_xor(mx0, o));
        mx1 = fmaxf(mx1, __shfl_xor(mx1, o));
    }

    float ls0 = 0.f, ld0 = 0.f, ls1 = 0.f, ld1 = 0.f;
    #pragma unroll
    for (int jt = 0; jt < 4; ++jt) {
        #pragma unroll
        for (int u = 0; u < 4; ++u) {
            int j = jt*128 + g*4 + u;
            float e0 = xa0 - xs[j*3+0], e1 = xa1 - xs[j*3+1], e2 = xa2 - xs[j*3+2];
            float ss = e0*e0 + e1*e1 + e2*e2;
            float dv0 = (ss > 0.f) ? sqrtf(ss) : 0.f;
            float f0 = xb0 - xs[j*3+0], f1 = xb1 - xs[j*3+1], f2 = xb2 - xs[j*3+2];
            float tt2 = f0*f0 + f1*f1 + f2*f2;
            float dv1 = (tt2 > 0.f) ? sqrtf(tt2) : 0.f;
            float p0 = __expf(sim0[jt*4+u] - mx0);
            float p1 = __expf(sim1[jt*4+u] - mx1);
            sim0[jt*4+u] = p0; sim1[jt*4+u] = p1;
            ls0 += p0; ld0 += p0 * dv0;
            ls1 += p1; ld1 += p1 * dv1;
        }
    }
    #pragma unroll
    for (int o = 1; o <= 16; o <<= 1) {
        ls0 += __shfl_xor(ls0, o); ld0 += __shfl_xor(ld0, o);
        ls1 += __shfl_xor(ls1, o); ld1 += __shfl_xor(ld1, o);
    }

    float acc0[32], acc1[32];
    #pragma unroll
    for (int d = 0; d < 32; ++d) { acc0[d] = 0.f; acc1[d] = 0.f; }

    #pragma unroll
    for (int jt = 0; jt < 4; ++jt) {
        __syncthreads();
        {
            const float* src = vbase + (size_t)(jt*128 + scol) * INNER + d0;
            float4 a0 = *(const float4*)(src + 0);
            float4 a1 = *(const float4*)(src + 4);
            float4 a2 = *(const float4*)(src + 8);
            float4 a3 = *(const float4*)(src + 12);
            Tt[(d0+ 0)*128 + scol] = a0.x; Tt[(d0+ 1)*128 + scol] = a0.y;
            Tt[(d0+ 2)*128 + scol] = a0.z; Tt[(d0+ 3)*128 + scol] = a0.w;
            Tt[(d0+ 4)*128 + scol] = a1.x; Tt[(d0+ 5)*128 + scol] = a1.y;
            Tt[(d0+ 6)*128 + scol] = a1.z; Tt[(d0+ 7)*128 + scol] = a1.w;
            Tt[(d0+ 8)*128 + scol] = a2.x; Tt[(d0+ 9)*128 + scol] = a2.y;
            Tt[(d0+10)*128 + scol] = a2.z; Tt[(d0+11)*128 + scol] = a2.w;
            Tt[(d0+12)*128 + scol] = a3.x; Tt[(d0+13)*128 + scol] = a3.y;
            Tt[(d0+14)*128 + scol] = a3.z; Tt[(d0+15)*128 + scol] = a3.w;
        }
        __syncthreads();
        float p00 = sim0[jt*4+0], p01 = sim0[jt*4+1], p02 = sim0[jt*4+2], p03 = sim0[jt*4+3];
        float p10 = sim1[jt*4+0], p11 = sim1[jt*4+1], p12 = sim1[jt*4+2], p13 = sim1[jt*4+3];
        #pragma unroll
        for (int d = 0; d < 32; ++d) {
            float4 vv = *(const float4*)&Tt[d*128 + g*4];
            acc0[d] += p00*vv.x + p01*vv.y + p02*vv.z + p03*vv.w;
            acc1[d] += p10*vv.x + p11*vv.y + p12*vv.z + p13*vv.w;
        }
    }

    #pragma unroll
    for (int d = 0; d < 32; ++d) {
        #pragma unroll
        for (int o = 1; o <= 16; o <<= 1) {
            acc0[d] += __shfl_xor(acc0[d], o);
            acc1[d] += __shfl_xor(acc1[d], o);
        }
    }

    float il0 = 1.0f / ls0, il1 = 1.0f / ls1;
    float ad0 = ld0 * il0, ad1 = ld1 * il1;
    float o0 = acc0[0], o1 = acc1[0];
    #pragma unroll
    for (int d = 1; d < 32; ++d) if (g == d) { o0 = acc0[d]; o1 = acc1[d]; }
    float wv = We[layer*INNER + h*DHEAD + g];
    float bv = be[layer*INNER + h*DHEAD + g];
    attnout[(size_t)(b*N + i0)*INNER + h*DHEAD + g] = o0*il0 + ad0*wv + bv;
    attnout[(size_t)(b*N + i1)*INNER + h*DHEAD + g] = o1*il1 + ad1*wv + bv;
}

// ------------- O GEMM: obuf = attnout @ Wo + bo (unchanged, proven) -------------
__global__ __launch_bounds__(256, 4)
void k_gemm_o(const float* __restrict__ attnout, const float* __restrict__ Wo,
              const float* __restrict__ bo, float* __restrict__ obuf, int layer) {
    __shared__ float AT[64][32];
    __shared__ float Bs[64][32];
    int tid = threadIdx.x;
    int mt = blockIdx.x & 31, nt = blockIdx.x >> 5;
    int tx = tid & 7, ty = tid >> 3;

    float acc[4] = {0,0,0,0};
    int am = tid & 31, ak = tid >> 5;
    int bn4 = tid & 7, bk = tid >> 3;
    const float* Wsrc = Wo + (size_t)layer*256*256 + nt*32;

    for (int kt = 0; kt < 4; ++kt) {
        int kbase = kt * 64;
        if (kt) __syncthreads();
        {
            const float* src = attnout + (size_t)(mt*32 + am)*256 + kbase + ak*8;
            float4 a0 = *(const float4*)src;
            float4 a1 = *(const float4*)(src + 4);
            AT[ak*8+0][am]=a0.x; AT[ak*8+1][am]=a0.y; AT[ak*8+2][am]=a0.z; AT[ak*8+3][am]=a0.w;
            AT[ak*8+4][am]=a1.x; AT[ak*8+5][am]=a1.y; AT[ak*8+6][am]=a1.z; AT[ak*8+7][am]=a1.w;
        }
        #pragma unroll
        for (int p = 0; p < 2; ++p) {
            int k = bk + p*32;
            *(float4*)&Bs[k][bn4*4] = *(const float4*)(Wsrc + (size_t)(kbase + k)*256 + bn4*4);
        }
        __syncthreads();
        #pragma unroll 8
        for (int k = 0; k < 64; ++k) {
            float a = AT[k][ty];
            float4 b = *(const float4*)&Bs[k][tx*4];
            acc[0] += a*b.x; acc[1] += a*b.y; acc[2] += a*b.z; acc[3] += a*b.w;
        }
    }
    int row = mt*32 + ty, n = nt*32 + tx*4;
    float4 bias = *(const float4*)&bo[layer*256 + n];
    float4 o = make_float4(acc[0]+bias.x, acc[1]+bias.y, acc[2]+bias.z, acc[3]+bias.w);
    *(float4*)&obuf[(size_t)row*256 + n] = o;
}

// ------------- final gate + residual + decode (layer 1) -------------
__global__ void k_gate_dec(const float* __restrict__ obuf, const float* __restrict__ Wg,
                           const float* __restrict__ nodes2, const float* __restrict__ Wdec,
                           float* __restrict__ out) {
    __shared__ float red4[4];
    int row = blockIdx.x, d = threadIdx.x;
    float o  = obuf[row*DIM + d];
    float nd = nodes2[row*DIM + d];
    const float* Wgl = Wg + 3*DIM;      // layer 1
    float s = o*Wgl[d] + nd*Wgl[DIM+d] + (o-nd)*Wgl[2*DIM+d];
    float tot = block_sum256(s, red4);
    float gate = 1.0f/(1.0f + __expf(-tot));
    float nn = o*gate + nd*(1.0f - gate);
    float s0 = block_sum256(nn * Wdec[d*3+0], red4);
    float s1 = block_sum256(nn * Wdec[d*3+1], red4);
    float s2 = block_sum256(nn * Wdec[d*3+2], red4);
    if (d == 0) { out[row*3+0] = s0; out[row*3+1] = s1; out[row*3+2] = s2; }
}

extern "C" void kernel_launch(void* const* d_in, const int* in_sizes, int n_in,
                              void* d_out, int out_size, void* d_ws, size_t ws_size,
                              hipStream_t stream) {
    const float* x     = (const float*)d_in[0];
    const float* t     = (const float*)d_in[1];
    const float* W_enc = (const float*)d_in[2];
    const float* W_dec = (const float*)d_in[3];
    const float* ln_g  = (const float*)d_in[4];
    const float* ln_b  = (const float*)d_in[5];
    const float* Wq    = (const float*)d_in[6];
    const float* bq    = (const float*)d_in[7];
    const float* Wkv   = (const float*)d_in[8];
    const float* bkv   = (const float*)d_in[9];
    const float* We    = (const float*)d_in[10];
    const float* be    = (const float*)d_in[11];
    const float* Wo    = (const float*)d_in[12];
    const float* bo    = (const float*)d_in[13];
    const float* Wg    = (const float*)d_in[14];
    float* out = (float*)d_out;

    float* ws = (float*)d_ws;
    float* nodes   = ws;                        // encode output (l0 residual input)
    float* nodes2  = nodes   + B*N*DIM;         // post-l0 residual (for gate_dec)
    float* qbuf    = nodes2  + B*N*DIM;
    float* kbuf    = qbuf    + B*N*INNER;
    float* vbuf    = kbuf    + B*N*INNER;
    float* qwe     = vbuf    + B*N*INNER;
    float* qbe     = qwe     + B*HEADS*N;
    float* attnout = qbe     + B*HEADS*N;
    float* obuf    = attnout + B*N*INNER;

    // layer 0: qkv writes encode into nodes2 slot? No — l0 writes `nodes` (encode);
    // l1 reads `nodes`, writes `nodes2` (post-l0 residual). Map accordingly:
    // k_qkv(layer=0): nodes2 param <- nodes buffer (encode written there)
    // k_qkv(layer=1): nodes param <- nodes buffer, nodes2 param <- nodes2 buffer
    k_qkv<<<384, 256, 0, stream>>>(x, t, W_enc, obuf, nodes, nodes, Wg, ln_g, ln_b,
                                   Wq, bq, Wkv, bkv, We, be,
                                   qbuf, kbuf, vbuf, qwe, qbe, 0);
    k_attn<<<B*HEADS*(N/TI), 256, 0, stream>>>(x, qbuf, kbuf, vbuf, qwe, qbe, We, be,
                                               attnout, 0);
    k_gemm_o<<<256, 256, 0, stream>>>(attnout, Wo, bo, obuf, 0);

    k_qkv<<<384, 256, 0, stream>>>(x, t, W_enc, obuf, nodes, nodes2, Wg, ln_g, ln_b,
                                   Wq, bq, Wkv, bkv, We, be,
                                   qbuf, kbuf, vbuf, qwe, qbe, 1);
    k_attn<<<B*HEADS*(N/TI), 256, 0, stream>>>(x, qbuf, kbuf, vbuf, qwe, qbe, We, be,
                                               attnout, 1);
    k_gemm_o<<<256, 256, 0, stream>>>(attnout, Wo, bo, obuf, 1);

    k_gate_dec<<<B*N, 256, 0, stream>>>(obuf, Wg, nodes2, W_dec, out);
}

// Round 13
// 112.023 us; speedup vs baseline: 1.0937x; 1.0937x over previous
//
#include <hip/hip_runtime.h>
#include <math.h>

#define B 2
#define N 512
#define DIM 256
#define HEADS 8
#define DHEAD 32
#define INNER 256
#define DEPTH 2
#define SCALE 0.17677669529663687f

// ---- block-wide sum over 256 threads (4 waves), result broadcast to all ----
__device__ __forceinline__ float block_sum256(float v, float* red4) {
    #pragma unroll
    for (int o = 32; o; o >>= 1) v += __shfl_xor(v, o);
    int tid = threadIdx.x;
    __syncthreads();                       // protect prior reads of red4
    if ((tid & 63) == 0) red4[tid >> 6] = v;
    __syncthreads();
    return red4[0] + red4[1] + red4[2] + red4[3];
}

// ------- fused: rotary tables (8 entries/block, f32) + encode + LN0 + dist -------
__global__ void k_pre(const float* __restrict__ x, const float* __restrict__ t,
                      const float* __restrict__ Wenc,
                      const float* __restrict__ ln_g, const float* __restrict__ ln_b,
                      float* __restrict__ nodes, float* __restrict__ hbuf,
                      float* __restrict__ dist,
                      float* __restrict__ ct, float* __restrict__ st) {
    __shared__ float red4[4];
    __shared__ float xs[N * 3];
    int row = blockIdx.x, d = threadIdx.x;
    int b = row >> 9, i = row & (N - 1);

    if (d < 8) {                           // rotary tables: 8192 entries / 1024 blocks
        int idx = blockIdx.x * 8 + d;
        int ii = idx >> 4, jj = idx & 15;
        float invf = powf(10000.0f, -(float)jj / 16.0f);
        float ang = (float)ii * invf;
        ct[idx] = cosf(ang);
        st[idx] = sinf(ang);
    }

    // encode + LN(layer 0)
    float x0 = x[row*3+0], x1 = x[row*3+1], x2 = x[row*3+2], tt = t[row];
    float nv = x0*Wenc[d] + x1*Wenc[DIM+d] + x2*Wenc[2*DIM+d] + tt*Wenc[3*DIM+d];
    nodes[row*DIM + d] = nv;
    float mean = block_sum256(nv, red4) * (1.0f/DIM);
    float c = nv - mean;
    float var = block_sum256(c*c, red4) * (1.0f/DIM);
    hbuf[row*DIM + d] = c * (1.0f/sqrtf(var + 1e-5f)) * ln_g[d] + ln_b[d];

    // dist row i vs all j (x[b] staged in LDS)
    for (int f = d; f < N*3; f += 256) xs[f] = x[b*N*3 + f];
    __syncthreads();
    float xi0 = xs[i*3+0], xi1 = xs[i*3+1], xi2 = xs[i*3+2];
    for (int j = d; j < N; j += 256) {
        float d0 = xi0 - xs[j*3+0], d1 = xi1 - xs[j*3+1], d2 = xi2 - xs[j*3+2];
        float s = d0*d0 + d1*d1 + d2*d2;
        dist[(size_t)row*N + j] = (s > 0.f) ? sqrtf(s) : 0.f;
    }
}

// ------------- QKV GEMM + rotary + qwe/qbe epilogue -------------
__global__ __launch_bounds__(256, 4)
void k_gemm_qkv(const float* __restrict__ hbuf,
                const float* __restrict__ Wq, const float* __restrict__ bq,
                const float* __restrict__ Wkv, const float* __restrict__ bkv,
                const float* __restrict__ We, const float* __restrict__ be,
                const float* __restrict__ ct, const float* __restrict__ st,
                float* __restrict__ qbuf, float* __restrict__ kbuf, float* __restrict__ vbuf,
                float* __restrict__ qwe, float* __restrict__ qbe, int layer) {
    __shared__ float AT[64][32];
    __shared__ float Bs[64][64];

    int tid = threadIdx.x;
    int mt = blockIdx.x & 31;
    int nt = blockIdx.x >> 5;
    int tx = tid & 15, ty = tid >> 4;
    int n0 = nt * 64;

    const float* Wsrc; int wstride;
    if (n0 < 256) { Wsrc = Wq  + (size_t)layer*256*256 + n0;        wstride = 256; }
    else          { Wsrc = Wkv + (size_t)layer*256*512 + (n0-256);  wstride = 512; }

    float acc[2][4] = {{0,0,0,0},{0,0,0,0}};

    int am = tid & 31, ak = tid >> 5;
    int bn4 = tid & 15, bk = tid >> 4;

    for (int kt = 0; kt < 4; ++kt) {
        int kbase = kt * 64;
        if (kt) __syncthreads();
        {
            const float* src = hbuf + (size_t)(mt*32 + am)*256 + kbase + ak*8;
            float4 a0 = *(const float4*)src;
            float4 a1 = *(const float4*)(src + 4);
            AT[ak*8+0][am]=a0.x; AT[ak*8+1][am]=a0.y; AT[ak*8+2][am]=a0.z; AT[ak*8+3][am]=a0.w;
            AT[ak*8+4][am]=a1.x; AT[ak*8+5][am]=a1.y; AT[ak*8+6][am]=a1.z; AT[ak*8+7][am]=a1.w;
        }
        #pragma unroll
        for (int p = 0; p < 4; ++p) {
            int k = bk + p*16;
            float4 v = *(const float4*)(Wsrc + (size_t)(kbase + k)*wstride + bn4*4);
            *(float4*)&Bs[k][bn4*4] = v;
        }
        __syncthreads();
        #pragma unroll 8
        for (int k = 0; k < 64; ++k) {
            float2 a = *(const float2*)&AT[k][ty*2];
            float4 b = *(const float4*)&Bs[k][tx*4];
            acc[0][0] += a.x*b.x; acc[0][1] += a.x*b.y; acc[0][2] += a.x*b.z; acc[0][3] += a.x*b.w;
            acc[1][0] += a.y*b.x; acc[1][1] += a.y*b.y; acc[1][2] += a.y*b.z; acc[1][3] += a.y*b.w;
        }
    }

    int row = mt*32 + ty*2;
    int n = n0 + tx*4;

    float4 bias4;
    if (n0 < 256) bias4 = *(const float4*)&bq[layer*256 + n];
    else          bias4 = *(const float4*)&bkv[layer*512 + (n - 256)];
    #pragma unroll
    for (int r = 0; r < 2; ++r) {
        acc[r][0] += bias4.x; acc[r][1] += bias4.y; acc[r][2] += bias4.z; acc[r][3] += bias4.w;
    }

    if (n0 >= 512) {
        #pragma unroll
        for (int r = 0; r < 2; ++r) {
            float4 o = make_float4(acc[r][0], acc[r][1], acc[r][2], acc[r][3]);
            *(float4*)&vbuf[(size_t)(row + r)*256 + (n - 512)] = o;
        }
        return;
    }

    float* sh = &Bs[0][0];
    __syncthreads();
    #pragma unroll
    for (int r = 0; r < 2; ++r)
        #pragma unroll
        for (int c = 0; c < 4; ++c)
            sh[(ty*2 + r)*68 + tx*4 + c] = acc[r][c];
    __syncthreads();

    float wep[2] = {0.f, 0.f}, bep[2] = {0.f, 0.f};
    float val[2][4];
    #pragma unroll
    for (int r = 0; r < 2; ++r) {
        int ii = (row + r) & (N-1);
        #pragma unroll
        for (int c = 0; c < 4; ++c) {
            int tc = tx*4 + c;
            int dd = tc & 31, jj = tc & 15;
            float ca = ct[ii*16 + jj], sa = st[ii*16 + jj];
            int ptc = (dd < 16) ? tc + 16 : tc - 16;
            float sgn = (dd < 16) ? -1.f : 1.f;
            float partner = sh[(ty*2 + r)*68 + ptc];
            float rot = acc[r][c]*ca + sgn*partner*sa;
            val[r][c] = rot;
            if (n0 < 256) {
                wep[r] += rot * We[layer*256 + n0 + tc];
                bep[r] += rot * be[layer*256 + n0 + tc];
            }
        }
    }

    float* dst = (n0 < 256) ? qbuf : kbuf;
    int coln = (n0 < 256) ? n : n - 256;
    #pragma unroll
    for (int r = 0; r < 2; ++r) {
        float4 o = make_float4(val[r][0], val[r][1], val[r][2], val[r][3]);
        *(float4*)&dst[(size_t)(row + r)*256 + coln] = o;
    }

    if (n0 < 256) {
        #pragma unroll
        for (int r = 0; r < 2; ++r) {
            wep[r] += __shfl_xor(wep[r], 1); bep[r] += __shfl_xor(bep[r], 1);
            wep[r] += __shfl_xor(wep[r], 2); bep[r] += __shfl_xor(bep[r], 2);
            wep[r] += __shfl_xor(wep[r], 4); bep[r] += __shfl_xor(bep[r], 4);
        }
        if ((tid & 7) == 0) {
            int h = nt*2 + (tx >> 3);
            int bb = row >> 9;
            #pragma unroll
            for (int r = 0; r < 2; ++r) {
                int ii = (row + r) & (N-1);
                qwe[(bb*HEADS + h)*N + ii] = wep[r];
                qbe[(bb*HEADS + h)*N + ii] = bep[r];
            }
        }
    }
}

// ------------- attention: TI=16, 2 i-rows per thread, dist reg-cached -------------
#define TI 16
__global__ __launch_bounds__(256, 2)
void k_attn(const float* __restrict__ qbuf, const float* __restrict__ kbuf,
            const float* __restrict__ vbuf,
            const float* __restrict__ qwe, const float* __restrict__ qbe,
            const float* __restrict__ dist,
            const float* __restrict__ We, const float* __restrict__ be,
            float* __restrict__ attnout, int layer) {
    __shared__ float Tt[32 * 128];

    int t = threadIdx.x;
    int g = t & 31;
    int r = t >> 5;
    int bid = blockIdx.x;
    int itile = bid & 31;
    int h = (bid >> 5) & (HEADS-1);
    int b = bid >> 8;
    int i0 = itile * TI + r;
    int i1 = i0 + 8;

    int scol = t & 127;
    int d0   = (t >> 7) * 16;

    float q0[32], q1[32];
    {
        const float4* qp0 = (const float4*)(qbuf + (size_t)(b*N + i0) * INNER + h * DHEAD);
        const float4* qp1 = (const float4*)(qbuf + (size_t)(b*N + i1) * INNER + h * DHEAD);
        #pragma unroll
        for (int c = 0; c < 8; ++c) {
            float4 v0 = qp0[c], v1 = qp1[c];
            q0[c*4+0] = v0.x; q0[c*4+1] = v0.y; q0[c*4+2] = v0.z; q0[c*4+3] = v0.w;
            q1[c*4+0] = v1.x; q1[c*4+1] = v1.y; q1[c*4+2] = v1.z; q1[c*4+3] = v1.w;
        }
    }
    float qw0 = qwe[(b*HEADS + h)*N + i0], qb0 = qbe[(b*HEADS + h)*N + i0];
    float qw1 = qwe[(b*HEADS + h)*N + i1], qb1 = qbe[(b*HEADS + h)*N + i1];

    const float* kbase = kbuf + (size_t)b*N*INNER + h*DHEAD;
    const float* vbase = vbuf + (size_t)b*N*INNER + h*DHEAD;
    const float* drow0 = dist + (size_t)(b*N + i0) * N;
    const float* drow1 = dist + (size_t)(b*N + i1) * N;

    float sim0[16], sim1[16];
    float dv0r[16], dv1r[16];             // dist values cached across phases

    #pragma unroll
    for (int jt = 0; jt < 4; ++jt) {
        if (jt) __syncthreads();
        {
            const float* src = kbase + (size_t)(jt*128 + scol) * INNER + d0;
            float4 a0 = *(const float4*)(src + 0);
            float4 a1 = *(const float4*)(src + 4);
            float4 a2 = *(const float4*)(src + 8);
            float4 a3 = *(const float4*)(src + 12);
            Tt[(d0+ 0)*128 + scol] = a0.x; Tt[(d0+ 1)*128 + scol] = a0.y;
            Tt[(d0+ 2)*128 + scol] = a0.z; Tt[(d0+ 3)*128 + scol] = a0.w;
            Tt[(d0+ 4)*128 + scol] = a1.x; Tt[(d0+ 5)*128 + scol] = a1.y;
            Tt[(d0+ 6)*128 + scol] = a1.z; Tt[(d0+ 7)*128 + scol] = a1.w;
            Tt[(d0+ 8)*128 + scol] = a2.x; Tt[(d0+ 9)*128 + scol] = a2.y;
            Tt[(d0+10)*128 + scol] = a2.z; Tt[(d0+11)*128 + scol] = a2.w;
            Tt[(d0+12)*128 + scol] = a3.x; Tt[(d0+13)*128 + scol] = a3.y;
            Tt[(d0+14)*128 + scol] = a3.z; Tt[(d0+15)*128 + scol] = a3.w;
        }
        __syncthreads();
        float4 s0 = make_float4(0.f,0.f,0.f,0.f);
        float4 s1 = make_float4(0.f,0.f,0.f,0.f);
        #pragma unroll
        for (int d = 0; d < 32; ++d) {
            float4 kv = *(const float4*)&Tt[d*128 + g*4];
            float qa = q0[d], qc = q1[d];
            s0.x += qa*kv.x; s0.y += qa*kv.y; s0.z += qa*kv.z; s0.w += qa*kv.w;
            s1.x += qc*kv.x; s1.y += qc*kv.y; s1.z += qc*kv.z; s1.w += qc*kv.w;
        }
        float4 dv0 = *(const float4*)&drow0[jt*128 + g*4];
        float4 dv1 = *(const float4*)&drow1[jt*128 + g*4];
        dv0r[jt*4+0] = dv0.x; dv0r[jt*4+1] = dv0.y; dv0r[jt*4+2] = dv0.z; dv0r[jt*4+3] = dv0.w;
        dv1r[jt*4+0] = dv1.x; dv1r[jt*4+1] = dv1.y; dv1r[jt*4+2] = dv1.z; dv1r[jt*4+3] = dv1.w;
        sim0[jt*4+0] = (s0.x + dv0.x*qw0 + qb0) * SCALE;
        sim0[jt*4+1] = (s0.y + dv0.y*qw0 + qb0) * SCALE;
        sim0[jt*4+2] = (s0.z + dv0.z*qw0 + qb0) * SCALE;
        sim0[jt*4+3] = (s0.w + dv0.w*qw0 + qb0) * SCALE;
        sim1[jt*4+0] = (s1.x + dv1.x*qw1 + qb1) * SCALE;
        sim1[jt*4+1] = (s1.y + dv1.y*qw1 + qb1) * SCALE;
        sim1[jt*4+2] = (s1.z + dv1.z*qw1 + qb1) * SCALE;
        sim1[jt*4+3] = (s1.w + dv1.w*qw1 + qb1) * SCALE;
    }

    float mx0 = -1e30f, mx1 = -1e30f;
    #pragma unroll
    for (int v = 0; v < 16; ++v) { mx0 = fmaxf(mx0, sim0[v]); mx1 = fmaxf(mx1, sim1[v]); }
    #pragma unroll
    for (int o = 1; o <= 16; o <<= 1) {
        mx0 = fmaxf(mx0, __shfl_xor(mx0, o));
        mx1 = fmaxf(mx1, __shfl_xor(mx1, o));
    }

    float ls0 = 0.f, ld0 = 0.f, ls1 = 0.f, ld1 = 0.f;
    #pragma unroll
    for (int v = 0; v < 16; ++v) {
        float p0 = __expf(sim0[v] - mx0);
        float p1 = __expf(sim1[v] - mx1);
        sim0[v] = p0; sim1[v] = p1;
        ls0 += p0; ld0 += p0 * dv0r[v];
        ls1 += p1; ld1 += p1 * dv1r[v];
    }
    #pragma unroll
    for (int o = 1; o <= 16; o <<= 1) {
        ls0 += __shfl_xor(ls0, o); ld0 += __shfl_xor(ld0, o);
        ls1 += __shfl_xor(ls1, o); ld1 += __shfl_xor(ld1, o);
    }

    float acc0[32], acc1[32];
    #pragma unroll
    for (int d = 0; d < 32; ++d) { acc0[d] = 0.f; acc1[d] = 0.f; }

    #pragma unroll
    for (int jt = 0; jt < 4; ++jt) {
        __syncthreads();
        {
            const float* src = vbase + (size_t)(jt*128 + scol) * INNER + d0;
            float4 a0 = *(const float4*)(src + 0);
            float4 a1 = *(const float4*)(src + 4);
            float4 a2 = *(const float4*)(src + 8);
            float4 a3 = *(const float4*)(src + 12);
            Tt[(d0+ 0)*128 + scol] = a0.x; Tt[(d0+ 1)*128 + scol] = a0.y;
            Tt[(d0+ 2)*128 + scol] = a0.z; Tt[(d0+ 3)*128 + scol] = a0.w;
            Tt[(d0+ 4)*128 + scol] = a1.x; Tt[(d0+ 5)*128 + scol] = a1.y;
            Tt[(d0+ 6)*128 + scol] = a1.z; Tt[(d0+ 7)*128 + scol] = a1.w;
            Tt[(d0+ 8)*128 + scol] = a2.x; Tt[(d0+ 9)*128 + scol] = a2.y;
            Tt[(d0+10)*128 + scol] = a2.z; Tt[(d0+11)*128 + scol] = a2.w;
            Tt[(d0+12)*128 + scol] = a3.x; Tt[(d0+13)*128 + scol] = a3.y;
            Tt[(d0+14)*128 + scol] = a3.z; Tt[(d0+15)*128 + scol] = a3.w;
        }
        __syncthreads();
        float p00 = sim0[jt*4+0], p01 = sim0[jt*4+1], p02 = sim0[jt*4+2], p03 = sim0[jt*4+3];
        float p10 = sim1[jt*4+0], p11 = sim1[jt*4+1], p12 = sim1[jt*4+2], p13 = sim1[jt*4+3];
        #pragma unroll
        for (int d = 0; d < 32; ++d) {
            float4 vv = *(const float4*)&Tt[d*128 + g*4];
            acc0[d] += p00*vv.x + p01*vv.y + p02*vv.z + p03*vv.w;
            acc1[d] += p10*vv.x + p11*vv.y + p12*vv.z + p13*vv.w;
        }
    }

    #pragma unroll
    for (int d = 0; d < 32; ++d) {
        #pragma unroll
        for (int o = 1; o <= 16; o <<= 1) {
            acc0[d] += __shfl_xor(acc0[d], o);
            acc1[d] += __shfl_xor(acc1[d], o);
        }
    }

    float il0 = 1.0f / ls0, il1 = 1.0f / ls1;
    float ad0 = ld0 * il0, ad1 = ld1 * il1;
    float o0 = acc0[0], o1 = acc1[0];
    #pragma unroll
    for (int d = 1; d < 32; ++d) if (g == d) { o0 = acc0[d]; o1 = acc1[d]; }
    float wv = We[layer*INNER + h*DHEAD + g];
    float bv = be[layer*INNER + h*DHEAD + g];
    attnout[(size_t)(b*N + i0)*INNER + h*DHEAD + g] = o0*il0 + ad0*wv + bv;
    attnout[(size_t)(b*N + i1)*INNER + h*DHEAD + g] = o1*il1 + ad1*wv + bv;
}

// ------------- O GEMM: obuf = attnout @ Wo + bo -------------
__global__ __launch_bounds__(256, 4)
void k_gemm_o(const float* __restrict__ attnout, const float* __restrict__ Wo,
              const float* __restrict__ bo, float* __restrict__ obuf, int layer) {
    __shared__ float AT[64][32];
    __shared__ float Bs[64][32];
    int tid = threadIdx.x;
    int mt = blockIdx.x & 31, nt = blockIdx.x >> 5;
    int tx = tid & 7, ty = tid >> 3;

    float acc[4] = {0,0,0,0};
    int am = tid & 31, ak = tid >> 5;
    int bn4 = tid & 7, bk = tid >> 3;
    const float* Wsrc = Wo + (size_t)layer*256*256 + nt*32;

    for (int kt = 0; kt < 4; ++kt) {
        int kbase = kt * 64;
        if (kt) __syncthreads();
        {
            const float* src = attnout + (size_t)(mt*32 + am)*256 + kbase + ak*8;
            float4 a0 = *(const float4*)src;
            float4 a1 = *(const float4*)(src + 4);
            AT[ak*8+0][am]=a0.x; AT[ak*8+1][am]=a0.y; AT[ak*8+2][am]=a0.z; AT[ak*8+3][am]=a0.w;
            AT[ak*8+4][am]=a1.x; AT[ak*8+5][am]=a1.y; AT[ak*8+6][am]=a1.z; AT[ak*8+7][am]=a1.w;
        }
        #pragma unroll
        for (int p = 0; p < 2; ++p) {
            int k = bk + p*32;
            *(float4*)&Bs[k][bn4*4] = *(const float4*)(Wsrc + (size_t)(kbase + k)*256 + bn4*4);
        }
        __syncthreads();
        #pragma unroll 8
        for (int k = 0; k < 64; ++k) {
            float a = AT[k][ty];
            float4 b = *(const float4*)&Bs[k][tx*4];
            acc[0] += a*b.x; acc[1] += a*b.y; acc[2] += a*b.z; acc[3] += a*b.w;
        }
    }
    int row = mt*32 + ty, n = nt*32 + tx*4;
    float4 bias = *(const float4*)&bo[layer*256 + n];
    float4 o = make_float4(acc[0]+bias.x, acc[1]+bias.y, acc[2]+bias.z, acc[3]+bias.w);
    *(float4*)&obuf[(size_t)row*256 + n] = o;
}

// ------------- gate + residual, then LN(next) or decode -------------
__global__ void k_gate_ln(const float* __restrict__ obuf, const float* __restrict__ Wg,
                          const float* __restrict__ ln_g, const float* __restrict__ ln_b,
                          const float* __restrict__ Wdec,
                          float* __restrict__ nodes, float* __restrict__ hbuf,
                          float* __restrict__ out, int layer) {
    __shared__ float red4[4];
    int row = blockIdx.x, d = threadIdx.x;
    float o  = obuf[row*DIM + d];
    float nd = nodes[row*DIM + d];
    const float* Wgl = Wg + layer*3*DIM;
    float s = o*Wgl[d] + nd*Wgl[DIM+d] + (o-nd)*Wgl[2*DIM+d];
    float tot = block_sum256(s, red4);
    float gate = 1.0f/(1.0f + __expf(-tot));
    float nn = o*gate + nd*(1.0f - gate);
    nodes[row*DIM + d] = nn;
    if (layer == 0) {
        float mean = block_sum256(nn, red4) * (1.0f/DIM);
        float c = nn - mean;
        float var = block_sum256(c*c, red4) * (1.0f/DIM);
        hbuf[row*DIM + d] = c * (1.0f/sqrtf(var + 1e-5f)) * ln_g[DIM + d] + ln_b[DIM + d];
    } else {
        float s0 = block_sum256(nn * Wdec[d*3+0], red4);
        float s1 = block_sum256(nn * Wdec[d*3+1], red4);
        float s2 = block_sum256(nn * Wdec[d*3+2], red4);
        if (d == 0) { out[row*3+0] = s0; out[row*3+1] = s1; out[row*3+2] = s2; }
    }
}

extern "C" void kernel_launch(void* const* d_in, const int* in_sizes, int n_in,
                              void* d_out, int out_size, void* d_ws, size_t ws_size,
                              hipStream_t stream) {
    const float* x     = (const float*)d_in[0];
    const float* t     = (const float*)d_in[1];
    const float* W_enc = (const float*)d_in[2];
    const float* W_dec = (const float*)d_in[3];
    const float* ln_g  = (const float*)d_in[4];
    const float* ln_b  = (const float*)d_in[5];
    const float* Wq    = (const float*)d_in[6];
    const float* bq    = (const float*)d_in[7];
    const float* Wkv   = (const float*)d_in[8];
    const float* bkv   = (const float*)d_in[9];
    const float* We    = (const float*)d_in[10];
    const float* be    = (const float*)d_in[11];
    const float* Wo    = (const float*)d_in[12];
    const float* bo    = (const float*)d_in[13];
    const float* Wg    = (const float*)d_in[14];
    float* out = (float*)d_out;

    float* ws = (float*)d_ws;
    float* nodes   = ws;
    float* dist    = nodes   + B*N*DIM;
    float* hbuf    = dist    + B*N*N;
    float* qbuf    = hbuf    + B*N*DIM;
    float* kbuf    = qbuf    + B*N*INNER;
    float* vbuf    = kbuf    + B*N*INNER;
    float* qwe     = vbuf    + B*N*INNER;
    float* qbe     = qwe     + B*HEADS*N;
    float* attnout = qbe     + B*HEADS*N;
    float* obuf    = attnout + B*N*INNER;
    float* ct      = obuf    + B*N*DIM;
    float* st      = ct      + N*16;

    k_pre<<<B*N, DIM, 0, stream>>>(x, t, W_enc, ln_g, ln_b, nodes, hbuf, dist, ct, st);
    for (int l = 0; l < DEPTH; ++l) {
        k_gemm_qkv<<<384, 256, 0, stream>>>(hbuf, Wq, bq, Wkv, bkv, We, be, ct, st,
                                            qbuf, kbuf, vbuf, qwe, qbe, l);
        k_attn<<<B*HEADS*(N/TI), 256, 0, stream>>>(qbuf, kbuf, vbuf, qwe, qbe, dist, We, be,
                                                   attnout, l);
        k_gemm_o<<<256, 256, 0, stream>>>(attnout, Wo, bo, obuf, l);
        k_gate_ln<<<B*N, DIM, 0, stream>>>(obuf, Wg, ln_g, ln_b, W_dec, nodes, hbuf, out, l);
    }
}